// Round 4
// baseline (464.684 us; speedup 1.0000x reference)
//
#include <hip/hip_runtime.h>
#include <stdint.h>

// ---------------------------------------------------------------------------
// EfficientDet post-process in 3 dispatches:
//   memset (17 KB zero: hist0, h8, barrier/counters)
//   k_score : per-anchor max over 80 classes -> key + 12-bit global hist0
//   k_tail  : 64 co-resident blocks with device-atomic barriers:
//     P_A scan0 -> d0            (all blocks, redundant)
//     P_B stream keys: partial hist1 slabs (mid-12 | top12==d0) + sures0
//     P_C parallel-reduce hist1  (64-bin slice per block)
//     P_D scan1 -> d1; stream keys: matches(top24==prefix) -> arrM + h8,
//         sures1(mid>d1) -> arrS
//     P_E (master blk 63): h8 scan -> exact threshold T; build candidate set;
//         bitonic sort 2048 composite keys (score desc, idx asc) == exact
//         stable top-k; decode+clip+argmax -> cand arrays
//     P_F (workers 0..62): 1000x1000 IoU>0.5 bitmatrix -> sup
//     P_G (master): ffs-sweep greedy NMS (pay per KEPT box) + output
// In-kernel sync is safe: 64 blocks <= 256 CUs => all co-resident; handshakes
// use device-scope atomics + __threadfence (rocPRIM decoupled-lookback style).
// ---------------------------------------------------------------------------

#define NK 1000
#define CAP 2048
#define NCLS 80
#define NW 16
#define TAIL_BLOCKS 64
#define MASTER_BLK 63
#define ARRM_CAP 65536
typedef unsigned long long ull;

// Order-preserving float -> uint transform.
static inline __device__ unsigned fkey(float f) {
  unsigned u = __float_as_uint(f);
  return (u & 0x80000000u) ? ~u : (u | 0x80000000u);
}
static inline __device__ float fkey_inv(unsigned k) {
  unsigned u = (k & 0x80000000u) ? (k & 0x7fffffffu) : ~k;
  return __uint_as_float(u);
}

// Redundant per-block selection scan (works for blockDim 256 or 1024).
// Finds largest digit with suffix-count >= k; returns digit + count above it.
__device__ __forceinline__ void scan_select(const unsigned* __restrict__ gh, int nbins,
                                            unsigned k, unsigned* s_sum, unsigned* s_res,
                                            unsigned& digit, unsigned& cum_above) {
  const int t = threadIdx.x;
  const int chunk = nbins >> 8;
  if (t < 256) {
    unsigned s = 0;
    for (int b = 0; b < chunk; ++b) s += gh[t * chunk + b];
    s_sum[t] = s;
  }
  __syncthreads();
  if (t < 256) {
    unsigned ca = 0;
    for (int u = t + 1; u < 256; ++u) ca += s_sum[u];
    unsigned s = s_sum[t];
    if (ca < k && ca + s >= k) {  // exactly one thread
      unsigned cum = ca;
      for (int b = chunk - 1; b >= 0; --b) {
        unsigned c = gh[t * chunk + b];
        if (cum + c >= k) { s_res[0] = (unsigned)(t * chunk + b); s_res[1] = cum; break; }
        cum += c;
      }
    }
  }
  __syncthreads();
  digit = s_res[0];
  cum_above = s_res[1];
  __syncthreads();
}

// ---- K1: score + key + top-12-bit histogram --------------------------------
__global__ __launch_bounds__(256) void k_score(const float* __restrict__ cla,
                                               unsigned* __restrict__ keys,
                                               unsigned* __restrict__ hist0, int A) {
  __shared__ unsigned lh[4096];
  int t = threadIdx.x;
  for (int i = t; i < 4096; i += 256) lh[i] = 0u;
  __syncthreads();
  const int lane = t & 63, wib = t >> 6;
  const int gwave = blockIdx.x * 4 + wib, nwaves = gridDim.x * 4;
  const int q = lane >> 2, sub = lane & 3;  // 4 lanes per 320B anchor row
  const int ntask = (A + 15) >> 4;
  for (int task = gwave; task < ntask; task += nwaves) {
    int a = task * 16 + q;
    float m = -3.402823466e38f;
    if (a < A) {
      const float4* p = (const float4*)(cla + (size_t)a * NCLS);
#pragma unroll
      for (int j = 0; j < 5; ++j) {
        float4 v = p[sub + j * 4];
        m = fmaxf(m, fmaxf(fmaxf(v.x, v.y), fmaxf(v.z, v.w)));
      }
    }
    m = fmaxf(m, __shfl_xor(m, 1, 64));
    m = fmaxf(m, __shfl_xor(m, 2, 64));
    if (sub == 0 && a < A) {
      unsigned key = fkey(m);
      keys[a] = key;
      atomicAdd(&lh[key >> 20], 1u);
    }
  }
  __syncthreads();
  for (int i = t; i < 4096; i += 256) {
    unsigned c = lh[i];
    if (c) atomicAdd(&hist0[i], c);  // ~30 nonzero bins/block -> cheap
  }
}

// ---- K2: everything else, 64 co-resident blocks ----------------------------
// ctrs: [0]=cntS [1]=cntM [2]=bar1 [3]=bar2 [4]=bar3 [5]=flag_cand [6]=done_sup
__global__ __launch_bounds__(1024) void k_tail(
    const float* __restrict__ cla, const float* __restrict__ reg,
    const float* __restrict__ anchors, const int* __restrict__ hp,
    const int* __restrict__ wp, float* __restrict__ out,
    const unsigned* __restrict__ keys, const unsigned* __restrict__ hist0,
    unsigned* __restrict__ hist1, unsigned* __restrict__ hist1p,
    unsigned* __restrict__ h8, unsigned* __restrict__ ctrs,
    ull* __restrict__ arrS, ull* __restrict__ arrM, float4* __restrict__ cand_box,
    float* __restrict__ cand_area, float* __restrict__ cand_score,
    int* __restrict__ cand_cls, int* __restrict__ cand_valid, ull* __restrict__ sup,
    int A) {
  __shared__ unsigned s_sum[256];
  __shared__ unsigned s_res[2];
  __shared__ unsigned lh[4096];                // 16 KB
  __shared__ ull lbufS0[1024];                 // 8 KB
  __shared__ ull lbufM[256];
  __shared__ ull lbufS1[256];
  __shared__ __align__(16) ull bufC[CAP];      // 16 KB
  __shared__ float4 sbox[NK];                  // 16 KB
  __shared__ float sarea[NK];                  // 4 KB
  __shared__ ull keep_sh[NW];
  __shared__ unsigned lcnt0, lcntM, lcntS1, lbase0, lbaseM, lbaseS1, s_cntC;

  const int t = threadIdx.x;
  const int blk = blockIdx.x;
  const int stride = TAIL_BLOCKS * 1024;

  // ---- P_A: scan0 ----
  unsigned d0, ca0;
  scan_select(hist0, 4096, NK, s_sum, s_res, d0, ca0);
  const unsigned krem1 = NK - ca0;

  // ---- P_B: partial hist1 + sures0 ----
  for (int i = t; i < 4096; i += 1024) lh[i] = 0u;
  if (t == 0) lcnt0 = 0u;
  __syncthreads();
  for (int a = blk * 1024 + t; a < A; a += stride) {
    unsigned key = keys[a];
    unsigned top = key >> 20;
    if (top == d0) {
      atomicAdd(&lh[(key >> 8) & 0xFFFu], 1u);
    } else if (top > d0) {  // unconditionally in top-1000
      unsigned p = atomicAdd(&lcnt0, 1u);
      if (p < 1024) lbufS0[p] = ((ull)key << 32) | (ull)(~(unsigned)a);
    }
  }
  __syncthreads();
  for (int i = t; i < 4096; i += 1024) hist1p[blk * 4096 + i] = lh[i];
  if (t == 0) lbase0 = lcnt0 ? atomicAdd(&ctrs[0], lcnt0 < 1024u ? lcnt0 : 1024u) : 0u;
  __syncthreads();
  {
    unsigned n = lcnt0 < 1024u ? lcnt0 : 1024u;
    for (unsigned i = t; i < n; i += 1024) {
      unsigned p = lbase0 + i;
      if (p < 1024) arrS[p] = lbufS0[i];
    }
  }
  // bar1 arrive+wait
  __syncthreads(); __threadfence();
  if (t == 0) {
    atomicAdd(&ctrs[2], 1u);
    while (atomicAdd(&ctrs[2], 0u) < TAIL_BLOCKS) __builtin_amdgcn_s_sleep(16);
  }
  __syncthreads(); __threadfence();

  // ---- P_C: reduce hist1 slice (64 bins per block) ----
  if (t < 64) {
    int bin = blk * 64 + t;
    unsigned s = 0;
    for (int j = 0; j < TAIL_BLOCKS; ++j) s += hist1p[j * 4096 + bin];
    hist1[bin] = s;
  }
  // bar2
  __syncthreads(); __threadfence();
  if (t == 0) {
    atomicAdd(&ctrs[3], 1u);
    while (atomicAdd(&ctrs[3], 0u) < TAIL_BLOCKS) __builtin_amdgcn_s_sleep(16);
  }
  __syncthreads(); __threadfence();

  // ---- P_D: scan1 + second stream: matches + sures1 ----
  unsigned d1, ca1;
  scan_select(hist1, 4096, krem1, s_sum, s_res, d1, ca1);
  const unsigned krem2 = krem1 - ca1;
  const unsigned prefix24 = (d0 << 12) | d1;
  if (t == 0) { lcntM = 0u; lcntS1 = 0u; }
  __syncthreads();
  for (int a = blk * 1024 + t; a < A; a += stride) {
    unsigned key = keys[a];
    if ((key >> 8) == prefix24) {
      unsigned p = atomicAdd(&lcntM, 1u);
      if (p < 256) lbufM[p] = ((ull)key << 32) | (ull)(~(unsigned)a);
    } else if ((key >> 20) == d0 && ((key >> 8) & 0xFFFu) > d1) {
      unsigned p = atomicAdd(&lcntS1, 1u);
      if (p < 256) lbufS1[p] = ((ull)key << 32) | (ull)(~(unsigned)a);
    }
  }
  __syncthreads();
  if (t == 0) {
    unsigned nM = lcntM < 256u ? lcntM : 256u;
    unsigned nS = lcntS1 < 256u ? lcntS1 : 256u;
    lbaseM = nM ? atomicAdd(&ctrs[1], nM) : 0u;
    lbaseS1 = nS ? atomicAdd(&ctrs[0], nS) : 0u;
  }
  __syncthreads();
  {
    unsigned nM = lcntM < 256u ? lcntM : 256u;
    for (unsigned i = t; i < nM; i += 1024) {
      unsigned p = lbaseM + i;
      if (p < ARRM_CAP) {
        arrM[p] = lbufM[i];
        atomicAdd(&h8[(unsigned)(lbufM[i] >> 32) & 0xFFu], 1u);
      }
    }
    unsigned nS = lcntS1 < 256u ? lcntS1 : 256u;
    for (unsigned i = t; i < nS; i += 1024) {
      unsigned p = lbaseS1 + i;
      if (p < 1024) arrS[p] = lbufS1[i];
    }
  }
  // bar3 arrive
  __syncthreads(); __threadfence();
  if (t == 0) atomicAdd(&ctrs[4], 1u);

  if (blk == MASTER_BLK) {
    // wait bar3
    if (t == 0)
      while (atomicAdd(&ctrs[4], 0u) < TAIL_BLOCKS) __builtin_amdgcn_s_sleep(16);
    __syncthreads(); __threadfence();

    // ---- P_E: exact threshold + candidate set + sort + decode ----
    unsigned d2, ca2;
    scan_select(h8, 256, krem2, s_sum, s_res, d2, ca2);
    const unsigned T = (prefix24 << 8) | d2;  // exact 1000th-largest key

    if (t == 0) s_cntC = 0u;
    __syncthreads();
    unsigned nS = ctrs[0]; if (nS > 1024u) nS = 1024u;
    unsigned nM = ctrs[1]; if (nM > ARRM_CAP) nM = ARRM_CAP;
    for (unsigned i = t; i < nS; i += 1024) {
      unsigned p = atomicAdd(&s_cntC, 1u);
      if (p < CAP) bufC[p] = arrS[i];
    }
    for (unsigned i = t; i < nM; i += 1024) {
      ull pk = arrM[i];
      if ((unsigned)(pk >> 32) >= T) {
        unsigned p = atomicAdd(&s_cntC, 1u);
        if (p < CAP) bufC[p] = pk;
      }
    }
    __syncthreads();
    unsigned nC = s_cntC < (unsigned)CAP ? s_cntC : (unsigned)CAP;
    for (int i = t; i < CAP; i += 1024)
      if ((unsigned)i >= nC) bufC[i] = 0ull;
    __syncthreads();
    // bitonic sort descending: exact stable top-k order (score desc, idx asc)
    for (unsigned k2 = 2; k2 <= CAP; k2 <<= 1) {
      for (unsigned j = k2 >> 1; j > 0; j >>= 1) {
        for (int i = t; i < CAP; i += 1024) {
          int ixj = i ^ (int)j;
          if (ixj > i) {
            ull x = bufC[i], y = bufC[ixj];
            bool up = ((i & k2) == 0);
            if (up ? (x < y) : (x > y)) { bufC[i] = y; bufC[ixj] = x; }
          }
        }
        __syncthreads();
      }
    }
    // decode + argmax for ranks 0..999
    if (t < NK) {
      ull ck = bufC[t];
      unsigned a = ~(unsigned)(ck & 0xFFFFFFFFull);
      float score = fkey_inv((unsigned)(ck >> 32));
      float W1 = (float)wp[0] - 1.0f;
      float H1 = (float)hp[0] - 1.0f;
      float4 dd = ((const float4*)reg)[a];
      float4 an = ((const float4*)anchors)[a];
      float wa = an.z - an.x, ha = an.w - an.y;
      float cxa = an.x + 0.5f * wa, cya = an.y + 0.5f * ha;
      float cx = cxa + dd.x * wa, cy = cya + dd.y * ha;
      float w = wa * expf(dd.z), h = ha * expf(dd.w);
      float x1 = fminf(fmaxf(cx - 0.5f * w, 0.0f), W1);
      float y1 = fminf(fmaxf(cy - 0.5f * h, 0.0f), H1);
      float x2 = fminf(fmaxf(cx + 0.5f * w, 0.0f), W1);
      float y2 = fminf(fmaxf(cy + 0.5f * h, 0.0f), H1);
      cand_box[t] = make_float4(x1, y1, x2, y2);
      cand_area[t] = fmaxf(x2 - x1, 0.0f) * fmaxf(y2 - y1, 0.0f);
      cand_score[t] = score;
      cand_valid[t] = (score > 0.5f) ? 1 : 0;
      const float* rowp = cla + (size_t)a * NCLS;
      float m = -3.402823466e38f;
      int ci = 0;
#pragma unroll
      for (int j = 0; j < NCLS; ++j) {
        float v = rowp[j];
        if (v > m) { m = v; ci = j; }
      }
      cand_cls[t] = ci;
    }
    __syncthreads(); __threadfence();
    if (t == 0) atomicExch(&ctrs[5], 1u);  // flag: candidates ready

    // wait for workers' supmat
    if (t == 0)
      while (atomicAdd(&ctrs[6], 0u) < TAIL_BLOCKS - 1) __builtin_amdgcn_s_sleep(16);
    __syncthreads(); __threadfence();

    // ---- P_G: ffs-sweep greedy NMS (wave 0) ----
    if (t < 64) {
      const int lane = t;
      ull keepw[NW];
#pragma unroll
      for (int c = 0; c < NW; ++c) {
        const int row = c * 64 + lane;
        ull rw[NW];
        int vld = 0;
        if (row < NK) {
#pragma unroll
          for (int w = 0; w < NW; ++w) rw[w] = sup[(size_t)row * NW + w];
          vld = cand_valid[row];
        } else {
#pragma unroll
          for (int w = 0; w < NW; ++w) rw[w] = 0ull;
        }
        ull prev = 0ull;
#pragma unroll
        for (int w = 0; w < NW; ++w)
          if (w < c) prev |= rw[w] & keepw[w];
        bool candf = vld && (prev == 0ull);
        ull remaining = __ballot(candf);
        ull Lc = rw[c];
        ull kept = 0ull;
        while (remaining) {
          int b = (int)__builtin_ctzll(remaining);
          ull Lb = __shfl(Lc, b, 64);  // row b's diagonal word (IoU symmetric)
          kept |= (1ull << b);
          remaining &= ~Lb;
          remaining &= ~(1ull << b);
        }
        keepw[c] = kept;
      }
      if (lane == 0)
#pragma unroll
        for (int w = 0; w < NW; ++w) keep_sh[w] = keepw[w];
    }
    __syncthreads();
    if (t < NK) {
      bool kp = (keep_sh[t >> 6] >> (t & 63)) & 1ull;
      out[t] = kp ? cand_score[t] : 0.0f;
      out[NK + t] = kp ? (float)cand_cls[t] : -1.0f;  // int output read as float
      float4 b = cand_box[t];
      ((float4*)(out + 2 * NK))[t] = kp ? b : make_float4(0.f, 0.f, 0.f, 0.f);
    }
  } else {
    // ---- P_F: workers — IoU bitmatrix ----
    if (t == 0)
      while (atomicAdd(&ctrs[5], 0u) < 1u) __builtin_amdgcn_s_sleep(16);
    __syncthreads(); __threadfence();
    for (int i = t; i < NK; i += 1024) {
      sbox[i] = cand_box[i];
      sarea[i] = cand_area[i];
    }
    __syncthreads();
    if (t < 256) {
      int i = blk * 16 + (t >> 4);
      int w = t & 15;
      if (i < NK) {
        float4 bi = sbox[i];
        float ai = sarea[i];
        ull bits = 0ull;
        int j0 = w * 64;
        int jend = (j0 + 64 < NK) ? (j0 + 64) : NK;
        for (int j = j0; j < jend; ++j) {
          float4 bj = sbox[j];
          float xx1 = fmaxf(bi.x, bj.x), yy1 = fmaxf(bi.y, bj.y);
          float xx2 = fminf(bi.z, bj.z), yy2 = fminf(bi.w, bj.w);
          float inter = fmaxf(xx2 - xx1, 0.0f) * fmaxf(yy2 - yy1, 0.0f);
          float uni = ai + sarea[j] - inter;
          float iou = inter / fmaxf(uni, 1e-8f);
          if (iou > 0.5f) bits |= (1ull << (j - j0));
        }
        sup[(size_t)i * NW + w] = bits;
      }
    }
    __syncthreads(); __threadfence();
    if (t == 0) atomicAdd(&ctrs[6], 1u);
  }
}

extern "C" void kernel_launch(void* const* d_in, const int* in_sizes, int n_in,
                              void* d_out, int out_size, void* d_ws, size_t ws_size,
                              hipStream_t stream) {
  const float* cla = (const float*)d_in[0];
  const float* reg = (const float*)d_in[1];
  const float* anchors = (const float*)d_in[2];
  const int* hp = (const int*)d_in[3];
  const int* wp = (const int*)d_in[4];
  float* out = (float*)d_out;
  int A = in_sizes[2] / 4;  // 441936

  char* ws = (char*)d_ws;
  size_t off = 0;
  auto carve = [&](size_t bytes) -> void* {
    void* p = ws + off;
    off += bytes;
    off = (off + 255) & ~(size_t)255;
    return p;
  };
  unsigned* keys = (unsigned*)carve((size_t)A * 4);
  // zero region: hist0 | h8 | ctrs (contiguous, 256-aligned sizes)
  char* zbase = ws + off;
  unsigned* hist0 = (unsigned*)carve(4096 * 4);
  unsigned* h8 = (unsigned*)carve(256 * 4);
  unsigned* ctrs = (unsigned*)carve(16 * 4);
  size_t zbytes = (size_t)((ws + off) - zbase);
  unsigned* hist1 = (unsigned*)carve(4096 * 4);
  unsigned* hist1p = (unsigned*)carve((size_t)TAIL_BLOCKS * 4096 * 4);
  ull* arrS = (ull*)carve(1024 * 8);
  ull* arrM = (ull*)carve((size_t)ARRM_CAP * 8);
  float4* cand_box = (float4*)carve(1024 * 16);
  float* cand_area = (float*)carve(1024 * 4);
  float* cand_score = (float*)carve(1024 * 4);
  int* cand_cls = (int*)carve(1024 * 4);
  int* cand_valid = (int*)carve(1024 * 4);
  ull* sup = (ull*)carve((size_t)1024 * NW * 8);
  (void)ws_size;
  (void)n_in;
  (void)out_size;

  hipMemsetAsync(zbase, 0, zbytes, stream);
  k_score<<<1024, 256, 0, stream>>>(cla, keys, hist0, A);
  k_tail<<<TAIL_BLOCKS, 1024, 0, stream>>>(cla, reg, anchors, hp, wp, out, keys, hist0,
                                           hist1, hist1p, h8, ctrs, arrS, arrM, cand_box,
                                           cand_area, cand_score, cand_cls, cand_valid,
                                           sup, A);
}